// Round 1
// baseline (436.373 us; speedup 1.0000x reference)
//
#include <hip/hip_runtime.h>
#include <hip/hip_bf16.h>

// TemporalDownScaleAttention: G=16384 groups x (4 tokens, D=512), H=8 heads x 64.
// Fused single kernel: 16 groups/block, 64 token rows, 4 waves, bf16 MFMA 16x16x32.
// Weights pre-swizzled to MFMA B-fragment order in d_ws (bf16, 2 MB).

#define DIM 512
#define GB 16
#define ROWS 64
#define WSZ 262144  // bf16 elements per weight (32 ntiles * 16 ksteps * 64 lanes * 8)

typedef __attribute__((ext_vector_type(8))) short bf8;     // 8 bf16 = 4 VGPR (MFMA A/B frag)
typedef __attribute__((ext_vector_type(4))) float f32x4;   // MFMA C/D frag

__device__ __forceinline__ ushort f2bs(float f) {
  union { __hip_bfloat16 b; ushort u; } c; c.b = __float2bfloat16(f); return c.u;
}
__device__ __forceinline__ float bs2f(ushort u) {
  union { unsigned int i; float f; } c; c.i = ((unsigned int)u) << 16; return c.f;
}
__device__ __forceinline__ unsigned int pack2(float a, float b) {
  return (unsigned int)f2bs(a) | ((unsigned int)f2bs(b) << 16);
}

// ---- prep: weights -> bf16 MFMA B-fragment order ----
// ws[widx][nt][ks][lane][j] = W[n][k],  n = nt*16+(lane&15), k = ks*32+(lane>>4)*8+j
// widx: 0=Wk, 1=Wv, 2=Wq, 3=Wo
__global__ void prep_w(const float* __restrict__ ipw, const float* __restrict__ opw,
                       ushort* __restrict__ ws) {
  int gid = blockIdx.x * 256 + threadIdx.x;   // 0..131071
  int widx = gid >> 15;
  int rem  = gid & 32767;
  int nt   = rem >> 10;
  int ks   = (rem >> 6) & 15;
  int lane = rem & 63;
  int n  = nt * 16 + (lane & 15);
  int k0 = ks * 32 + (lane >> 4) * 8;
  const float* src;
  if      (widx == 0) src = ipw + (size_t)(512  + n) * DIM;  // Wk
  else if (widx == 1) src = ipw + (size_t)(1024 + n) * DIM;  // Wv
  else if (widx == 2) src = ipw + (size_t)n * DIM;           // Wq
  else                src = opw + (size_t)n * DIM;           // Wo
  ushort* dst = ws + (size_t)gid * 8;
#pragma unroll
  for (int j = 0; j < 8; ++j) dst[j] = f2bs(src[k0 + j]);
}

// ---- LDS layout (bytes) ----
#define LDS_E   0        // E   [64][512] bf16 swizzled  (65536)
#define LDS_S16 65536    // QBAR -> QH-scratch -> CTX [16][512] bf16 (16384)
#define LDS_KV  81920    // KH -> VH [64][512] bf16 (65536)
#define LDS_AT  147456   // attn [16][8][4] f32 (2048)
#define LDS_TOT 149504

__device__ __forceinline__ int swz(int row, int kbyte) {
  return row * 1024 + (kbyte ^ ((row & 7) << 4));
}

__global__ __launch_bounds__(256, 1) void tdsa(
    const float* __restrict__ x, const float* __restrict__ pos,
    const float* __restrict__ ipb, const float* __restrict__ opb,
    const ushort* __restrict__ wf, float* __restrict__ out)
{
  extern __shared__ char lds[];
  const int tid  = threadIdx.x;
  const int lane = tid & 63;
  const int wave = tid >> 6;
  const int blk  = blockIdx.x;
  const size_t xbase = (size_t)blk * (ROWS * DIM);

  // ---- Phase 0: E = x + pos_emb -> LDS bf16 (swizzled) ----
#pragma unroll
  for (int ch = 0; ch < 16; ++ch) {
    int idx = ch * 256 + tid;
    int row = idx >> 6, c8 = idx & 63;
    const float4* xp = reinterpret_cast<const float4*>(x + xbase + (size_t)row * DIM + c8 * 8);
    float4 a = xp[0], b = xp[1];
    const float4* pp = reinterpret_cast<const float4*>(pos + (row & 3) * DIM + c8 * 8);
    float4 pa = pp[0], pb = pp[1];
    uint4 u;
    u.x = pack2(a.x + pa.x, a.y + pa.y);
    u.y = pack2(a.z + pa.z, a.w + pa.w);
    u.z = pack2(b.x + pb.x, b.y + pb.y);
    u.w = pack2(b.z + pb.z, b.w + pb.w);
    *reinterpret_cast<uint4*>(&lds[LDS_E + swz(row, c8 * 16)]) = u;
  }
  __syncthreads();

  // ---- Phase 0b: QBAR = mean over 4 tokens ----
#pragma unroll
  for (int ch = 0; ch < 4; ++ch) {
    int idx = ch * 256 + tid;
    int g = idx >> 6, c8 = idx & 63;
    float acc[8];
#pragma unroll
    for (int j = 0; j < 8; ++j) acc[j] = 0.f;
#pragma unroll
    for (int t = 0; t < 4; ++t) {
      int r = g * 4 + t;
      bf8 v = *reinterpret_cast<const bf8*>(&lds[LDS_E + swz(r, c8 * 16)]);
#pragma unroll
      for (int j = 0; j < 8; ++j) acc[j] += bs2f((ushort)v[j]);
    }
    uint4 u;
    u.x = pack2(acc[0] * 0.25f, acc[1] * 0.25f);
    u.y = pack2(acc[2] * 0.25f, acc[3] * 0.25f);
    u.z = pack2(acc[4] * 0.25f, acc[5] * 0.25f);
    u.w = pack2(acc[6] * 0.25f, acc[7] * 0.25f);
    *reinterpret_cast<uint4*>(&lds[LDS_S16 + swz(g, c8 * 16)]) = u;
  }
  __syncthreads();

  const int ct0 = wave * 8;  // this wave's first column-tile (cols ct0*16 ..)

  // ---- Phase 1: KH = E@WkT (+QH = QBAR@WqT), column-split across waves ----
  f32x4 accK[4][8];
  f32x4 accQ[8];
#pragma unroll
  for (int c = 0; c < 8; ++c) {
    accQ[c] = (f32x4){0.f, 0.f, 0.f, 0.f};
#pragma unroll
    for (int rt = 0; rt < 4; ++rt) accK[rt][c] = (f32x4){0.f, 0.f, 0.f, 0.f};
  }
  {
    const ushort* wk = wf;                     // widx 0
    const ushort* wq = wf + 2 * (size_t)WSZ;   // widx 2
    for (int ks = 0; ks < 16; ++ks) {
      int kbyte = ks * 64 + (lane >> 4) * 16;
      bf8 a[4], aq;
#pragma unroll
      for (int rt = 0; rt < 4; ++rt) {
        int r = rt * 16 + (lane & 15);
        a[rt] = *reinterpret_cast<const bf8*>(&lds[LDS_E + swz(r, kbyte)]);
      }
      { int r = lane & 15; aq = *reinterpret_cast<const bf8*>(&lds[LDS_S16 + swz(r, kbyte)]); }
      bf8 bk_[8], bq_[8];
#pragma unroll
      for (int c = 0; c < 8; ++c) {
        size_t fo = ((size_t)((ct0 + c) * 16 + ks) * 64 + lane) * 8;
        bk_[c] = *reinterpret_cast<const bf8*>(wk + fo);
        bq_[c] = *reinterpret_cast<const bf8*>(wq + fo);
      }
#pragma unroll
      for (int c = 0; c < 8; ++c) {
#pragma unroll
        for (int rt = 0; rt < 4; ++rt)
          accK[rt][c] = __builtin_amdgcn_mfma_f32_16x16x32_bf16(a[rt], bk_[c], accK[rt][c], 0, 0, 0);
        accQ[c] = __builtin_amdgcn_mfma_f32_16x16x32_bf16(aq, bq_[c], accQ[c], 0, 0, 0);
      }
    }
  }
  __syncthreads();  // all waves done reading QBAR before QH-scratch overwrites it

  // write KH (+bk) to KV region, QH (+bq) to S16 region (both own-strip, bf16)
#pragma unroll
  for (int c = 0; c < 8; ++c) {
    int gcol = (ct0 + c) * 16 + (lane & 15);
    float bk_b = ipb[512 + gcol];
    float bq_b = ipb[gcol];
#pragma unroll
    for (int j = 0; j < 4; ++j) {
      int rq = (lane >> 4) * 4 + j;
      *reinterpret_cast<ushort*>(&lds[LDS_S16 + swz(rq, gcol * 2)]) = f2bs(accQ[c][j] + bq_b);
#pragma unroll
      for (int rt = 0; rt < 4; ++rt) {
        int r = rt * 16 + rq;
        *reinterpret_cast<ushort*>(&lds[LDS_KV + swz(r, gcol * 2)]) = f2bs(accK[rt][c][j] + bk_b);
      }
    }
  }

  // ---- Phase 2: scores + softmax (wave w owns heads 2w, 2w+1 — all data own-wave) ----
#pragma unroll
  for (int i = 0; i < 2; ++i) {
    int item = i * 64 + lane;
    int g    = item >> 3;            // 0..15
    int hrel = (lane >> 2) & 1;
    int k    = lane & 3;
    int cb2  = wave * 256 + hrel * 128;  // byte col base of this head
    int r    = g * 4 + k;
    float dot = 0.f;
#pragma unroll
    for (int c = 0; c < 8; ++c) {
      int kb = cb2 + c * 16;
      bf8 qv = *reinterpret_cast<const bf8*>(&lds[LDS_S16 + swz(g, kb)]);
      bf8 kv = *reinterpret_cast<const bf8*>(&lds[LDS_KV + swz(r, kb)]);
#pragma unroll
      for (int j = 0; j < 8; ++j) dot += bs2f((ushort)qv[j]) * bs2f((ushort)kv[j]);
    }
    float s = dot * 0.125f;  // 1/sqrt(64)
    float m = fmaxf(s, __shfl_xor(s, 1));
    m = fmaxf(m, __shfl_xor(m, 2));
    float p = __expf(s - m);
    float sum = p + __shfl_xor(p, 1);
    sum += __shfl_xor(sum, 2);
    float a = p / sum;
    int h = wave * 2 + hrel;
    *reinterpret_cast<float*>(&lds[LDS_AT + ((g * 8 + h) * 4 + k) * 4]) = a;
  }

  // ---- Phase 3: VH = E@WvT (overwrites KH strip — own-wave only) ----
  f32x4 accV[4][8];
#pragma unroll
  for (int c = 0; c < 8; ++c)
#pragma unroll
    for (int rt = 0; rt < 4; ++rt) accV[rt][c] = (f32x4){0.f, 0.f, 0.f, 0.f};
  {
    const ushort* wv = wf + (size_t)WSZ;  // widx 1
    for (int ks = 0; ks < 16; ++ks) {
      int kbyte = ks * 64 + (lane >> 4) * 16;
      bf8 a[4];
#pragma unroll
      for (int rt = 0; rt < 4; ++rt) {
        int r = rt * 16 + (lane & 15);
        a[rt] = *reinterpret_cast<const bf8*>(&lds[LDS_E + swz(r, kbyte)]);
      }
      bf8 bv_[8];
#pragma unroll
      for (int c = 0; c < 8; ++c) {
        size_t fo = ((size_t)((ct0 + c) * 16 + ks) * 64 + lane) * 8;
        bv_[c] = *reinterpret_cast<const bf8*>(wv + fo);
      }
#pragma unroll
      for (int c = 0; c < 8; ++c)
#pragma unroll
        for (int rt = 0; rt < 4; ++rt)
          accV[rt][c] = __builtin_amdgcn_mfma_f32_16x16x32_bf16(a[rt], bv_[c], accV[rt][c], 0, 0, 0);
    }
  }
#pragma unroll
  for (int c = 0; c < 8; ++c) {
    int gcol = (ct0 + c) * 16 + (lane & 15);
    float bv_b = ipb[1024 + gcol];
#pragma unroll
    for (int j = 0; j < 4; ++j) {
      int rq = (lane >> 4) * 4 + j;
#pragma unroll
      for (int rt = 0; rt < 4; ++rt) {
        int r = rt * 16 + rq;
        *reinterpret_cast<ushort*>(&lds[LDS_KV + swz(r, gcol * 2)]) = f2bs(accV[rt][c][j] + bv_b);
      }
    }
  }
  __syncthreads();  // VH + attn visible to all; QH-scratch dead -> S16 reusable as CTX

  // ---- Phase 4: CTX[g][d] = sum_k attn[g,h(d),k] * VH[4g+k][d] ----
#pragma unroll
  for (int i = 0; i < 4; ++i) {
    int item = i * 256 + tid;
    int g = item >> 6, c8 = item & 63;
    int h = c8 >> 3;
    float aw[4];
#pragma unroll
    for (int k = 0; k < 4; ++k)
      aw[k] = *reinterpret_cast<float*>(&lds[LDS_AT + ((g * 8 + h) * 4 + k) * 4]);
    float acc[8];
#pragma unroll
    for (int j = 0; j < 8; ++j) acc[j] = 0.f;
#pragma unroll
    for (int k = 0; k < 4; ++k) {
      bf8 v = *reinterpret_cast<const bf8*>(&lds[LDS_KV + swz(g * 4 + k, c8 * 16)]);
#pragma unroll
      for (int j = 0; j < 8; ++j) acc[j] += aw[k] * bs2f((ushort)v[j]);
    }
    uint4 u;
    u.x = pack2(acc[0], acc[1]);
    u.y = pack2(acc[2], acc[3]);
    u.z = pack2(acc[4], acc[5]);
    u.w = pack2(acc[6], acc[7]);
    *reinterpret_cast<uint4*>(&lds[LDS_S16 + swz(g, c8 * 16)]) = u;
  }
  __syncthreads();

  // ---- Phase 5: OUT = CTX@WoT + bo ----
  f32x4 accO[8];
#pragma unroll
  for (int c = 0; c < 8; ++c) accO[c] = (f32x4){0.f, 0.f, 0.f, 0.f};
  {
    const ushort* wo = wf + 3 * (size_t)WSZ;
    for (int ks = 0; ks < 16; ++ks) {
      int kbyte = ks * 64 + (lane >> 4) * 16;
      int r = lane & 15;
      bf8 a0 = *reinterpret_cast<const bf8*>(&lds[LDS_S16 + swz(r, kbyte)]);
      bf8 bo_[8];
#pragma unroll
      for (int c = 0; c < 8; ++c) {
        size_t fo = ((size_t)((ct0 + c) * 16 + ks) * 64 + lane) * 8;
        bo_[c] = *reinterpret_cast<const bf8*>(wo + fo);
      }
#pragma unroll
      for (int c = 0; c < 8; ++c)
        accO[c] = __builtin_amdgcn_mfma_f32_16x16x32_bf16(a0, bo_[c], accO[c], 0, 0, 0);
    }
  }
#pragma unroll
  for (int c = 0; c < 8; ++c) {
    int gcol = (ct0 + c) * 16 + (lane & 15);
    float bb = opb[gcol];
#pragma unroll
    for (int j = 0; j < 4; ++j) {
      int g = (lane >> 4) * 4 + j;
      out[((size_t)blk * GB + g) * DIM + gcol] = accO[c][j] + bb;
    }
  }
}

extern "C" void kernel_launch(void* const* d_in, const int* in_sizes, int n_in,
                              void* d_out, int out_size, void* d_ws, size_t ws_size,
                              hipStream_t stream) {
  const float* x   = (const float*)d_in[0];
  const float* pos = (const float*)d_in[1];
  const float* ipw = (const float*)d_in[2];
  const float* ipb = (const float*)d_in[3];
  const float* opw = (const float*)d_in[4];
  const float* opb = (const float*)d_in[5];
  ushort* wsf = (ushort*)d_ws;  // 4 * 262144 bf16 = 2 MB

  prep_w<<<512, 256, 0, stream>>>(ipw, opw, wsf);

  hipFuncSetAttribute(reinterpret_cast<const void*>(tdsa),
                      hipFuncAttributeMaxDynamicSharedMemorySize, LDS_TOT);
  tdsa<<<1024, 256, LDS_TOT, stream>>>(x, pos, ipb, opb, wsf, (float*)d_out);
}

// Round 2
// 390.877 us; speedup vs baseline: 1.1164x; 1.1164x over previous
//
#include <hip/hip_runtime.h>
#include <hip/hip_bf16.h>

// TemporalDownScaleAttention: G=16384 groups x (4 tokens, D=512), H=8 heads x 64.
// R2: 32 groups/block (128 rows), 512 threads = 8 waves, wave w owns head w.
// KH/VH/attn stay in registers (lane-local softmax); LDS only for E + QBAR/QH/CTX.
// Weights pre-swizzled to MFMA B-fragment order in d_ws (bf16, 2 MB).

#define DIM 512
#define GB 32
#define ROWS 128
#define WSZ 262144  // bf16 elements per weight (32 ntiles * 16 ksteps * 64 lanes * 8)

typedef __attribute__((ext_vector_type(8))) short bf8;     // 8 bf16 = 4 VGPR (MFMA A/B frag)
typedef __attribute__((ext_vector_type(4))) float f32x4;   // MFMA C/D frag

__device__ __forceinline__ ushort f2bs(float f) {
  union { __hip_bfloat16 b; ushort u; } c; c.b = __float2bfloat16(f); return c.u;
}
__device__ __forceinline__ float bs2f(ushort u) {
  union { unsigned int i; float f; } c; c.i = ((unsigned int)u) << 16; return c.f;
}
__device__ __forceinline__ unsigned int pack2(float a, float b) {
  return (unsigned int)f2bs(a) | ((unsigned int)f2bs(b) << 16);
}

// ---- prep: weights -> bf16 MFMA B-fragment order ----
// ws[widx][nt][ks][lane][j] = W[n][k],  n = nt*16+(lane&15), k = ks*32+(lane>>4)*8+j
// widx: 0=Wk, 1=Wv, 2=Wq, 3=Wo
__global__ void prep_w(const float* __restrict__ ipw, const float* __restrict__ opw,
                       ushort* __restrict__ ws) {
  int gid = blockIdx.x * 256 + threadIdx.x;   // 0..131071
  int widx = gid >> 15;
  int rem  = gid & 32767;
  int nt   = rem >> 10;
  int ks   = (rem >> 6) & 15;
  int lane = rem & 63;
  int n  = nt * 16 + (lane & 15);
  int k0 = ks * 32 + (lane >> 4) * 8;
  const float* src;
  if      (widx == 0) src = ipw + (size_t)(512  + n) * DIM;  // Wk
  else if (widx == 1) src = ipw + (size_t)(1024 + n) * DIM;  // Wv
  else if (widx == 2) src = ipw + (size_t)n * DIM;           // Wq
  else                src = opw + (size_t)n * DIM;           // Wo
  ushort* dst = ws + (size_t)gid * 8;
#pragma unroll
  for (int j = 0; j < 8; ++j) dst[j] = f2bs(src[k0 + j]);
}

// ---- LDS layout (bytes) ----
// Region A: E [128 rows][1024 B] swizzled bf16            (131072)
// Region B: QBAR [32][1024 B] swz  ->  per-wave QH [8][4096 B]  ->  CTX [32][1024 B] swz
#define LDS_E   0
#define LDS_B   131072
#define LDS_TOT 163840   // 160 KiB exactly

__device__ __forceinline__ int swz(int row, int kbyte) {
  return row * 1024 + (kbyte ^ ((row & 7) << 4));
}

__global__ __launch_bounds__(512, 2) void tdsa(
    const float* __restrict__ x, const float* __restrict__ pos,
    const float* __restrict__ ipb, const float* __restrict__ opb,
    const ushort* __restrict__ wf, float* __restrict__ out)
{
  extern __shared__ char lds[];
  const int tid  = threadIdx.x;
  const int lane = tid & 63;
  const int wave = tid >> 6;     // 0..7 == head
  const int low  = lane & 15;
  const int qq   = lane >> 4;    // 0..3
  const int blk  = blockIdx.x;
  const size_t xbase = (size_t)blk * (ROWS * DIM);
  const int ct0 = wave * 4;      // first 16-col tile of this wave's head

  // ---- Phase 0: E = x + pos_emb -> LDS bf16 (swizzled) ----
#pragma unroll
  for (int ch = 0; ch < 16; ++ch) {
    int idx = ch * 512 + tid;              // 8192 items = 128 rows x 64 c8
    int row = idx >> 6, c8 = idx & 63;
    const float4* xp = reinterpret_cast<const float4*>(x + xbase + (size_t)row * DIM + c8 * 8);
    float4 a = xp[0], b = xp[1];
    const float4* pp = reinterpret_cast<const float4*>(pos + (row & 3) * DIM + c8 * 8);
    float4 pa = pp[0], pb = pp[1];
    uint4 u;
    u.x = pack2(a.x + pa.x, a.y + pa.y);
    u.y = pack2(a.z + pa.z, a.w + pa.w);
    u.z = pack2(b.x + pb.x, b.y + pb.y);
    u.w = pack2(b.z + pb.z, b.w + pb.w);
    *reinterpret_cast<uint4*>(&lds[LDS_E + swz(row, c8 * 16)]) = u;
  }
  __syncthreads();

  // ---- Phase 0b: QBAR = mean over 4 tokens -> region B ----
#pragma unroll
  for (int ch = 0; ch < 4; ++ch) {
    int idx = ch * 512 + tid;              // 2048 items = 32 g x 64 c8
    int g = idx >> 6, c8 = idx & 63;
    float acc[8];
#pragma unroll
    for (int j = 0; j < 8; ++j) acc[j] = 0.f;
#pragma unroll
    for (int t = 0; t < 4; ++t) {
      bf8 v = *reinterpret_cast<const bf8*>(&lds[LDS_E + swz(g * 4 + t, c8 * 16)]);
#pragma unroll
      for (int j = 0; j < 8; ++j) acc[j] += bs2f((ushort)v[j]);
    }
    uint4 u;
    u.x = pack2(acc[0] * 0.25f, acc[1] * 0.25f);
    u.y = pack2(acc[2] * 0.25f, acc[3] * 0.25f);
    u.z = pack2(acc[4] * 0.25f, acc[5] * 0.25f);
    u.w = pack2(acc[6] * 0.25f, acc[7] * 0.25f);
    *reinterpret_cast<uint4*>(&lds[LDS_B + swz(g, c8 * 16)]) = u;
  }
  __syncthreads();

  // ---- Phase 1: K-proj  accK[rt][c] = (E @ WkT) tile, cols of head `wave` ----
  // (bk bias dropped: constant over k within a (g,h) -> cancels in softmax; KH unused elsewhere)
  f32x4 accK[8][4];
#pragma unroll
  for (int rt = 0; rt < 8; ++rt)
#pragma unroll
    for (int c = 0; c < 4; ++c) accK[rt][c] = (f32x4){0.f, 0.f, 0.f, 0.f};
  {
    const ushort* wk = wf;
    for (int ks = 0; ks < 16; ++ks) {
      int kbyte = ks * 64 + qq * 16;
      bf8 a[8];
#pragma unroll
      for (int rt = 0; rt < 8; ++rt)
        a[rt] = *reinterpret_cast<const bf8*>(&lds[LDS_E + swz(rt * 16 + low, kbyte)]);
      bf8 bk_[4];
#pragma unroll
      for (int c = 0; c < 4; ++c) {
        size_t fo = ((size_t)((ct0 + c) * 16 + ks) * 64 + lane) * 8;
        bk_[c] = *reinterpret_cast<const bf8*>(wk + fo);
      }
#pragma unroll
      for (int c = 0; c < 4; ++c)
#pragma unroll
        for (int rt = 0; rt < 8; ++rt)
          accK[rt][c] = __builtin_amdgcn_mfma_f32_16x16x32_bf16(a[rt], bk_[c], accK[rt][c], 0, 0, 0);
    }
  }

  // ---- Phase 1b: Q-proj  accQ[rtq][c] (QBAR @ WqT), bq dropped (cancels in softmax) ----
  f32x4 accQ[2][4];
#pragma unroll
  for (int rt = 0; rt < 2; ++rt)
#pragma unroll
    for (int c = 0; c < 4; ++c) accQ[rt][c] = (f32x4){0.f, 0.f, 0.f, 0.f};
  {
    const ushort* wq = wf + 2 * (size_t)WSZ;
    for (int ks = 0; ks < 16; ++ks) {
      int kbyte = ks * 64 + qq * 16;
      bf8 aq[2];
#pragma unroll
      for (int rt = 0; rt < 2; ++rt)
        aq[rt] = *reinterpret_cast<const bf8*>(&lds[LDS_B + swz(rt * 16 + low, kbyte)]);
      bf8 bq_[4];
#pragma unroll
      for (int c = 0; c < 4; ++c) {
        size_t fo = ((size_t)((ct0 + c) * 16 + ks) * 64 + lane) * 8;
        bq_[c] = *reinterpret_cast<const bf8*>(wq + fo);
      }
#pragma unroll
      for (int c = 0; c < 4; ++c)
#pragma unroll
        for (int rt = 0; rt < 2; ++rt)
          accQ[rt][c] = __builtin_amdgcn_mfma_f32_16x16x32_bf16(aq[rt], bq_[c], accQ[rt][c], 0, 0, 0);
    }
  }
  __syncthreads();   // all waves done reading QBAR; region B reusable

  // ---- QH -> per-wave LDS scratch, layout [colLocal 0..63][j 0..3][g>>2 0..7] bf16 ----
  // QH[g][col]: g = rtq*16 + qq*4 + j_reg, col = (ct0+c)*16 + low
  // store addr = wave*4096 + colLocal*64 + (g&3)*16 + (g>>2)*2   (g&3 == j_reg, g>>2 == rtq*4+qq)
#pragma unroll
  for (int rtq = 0; rtq < 2; ++rtq)
#pragma unroll
    for (int c = 0; c < 4; ++c) {
      int colLocal = c * 16 + low;
#pragma unroll
      for (int j = 0; j < 4; ++j) {
        int addr = LDS_B + wave * 4096 + colLocal * 64 + j * 16 + (rtq * 4 + qq) * 2;
        *reinterpret_cast<ushort*>(&lds[addr]) = f2bs(accQ[rtq][c][j]);
      }
    }

  // ---- Phase 2: scores + softmax, fully lane-local ----
  // Lane holds KH[rtk*16 + qq*4 + j][col(c,low)] = KH[4g+k] with g = rtk*4+qq, k = j.
  // Needs QH[g=rtk*4+qq][col]: read own-wave scratch, one b128 per c gives all 8 rtk.
  float sp[8][4];
#pragma unroll
  for (int rt = 0; rt < 8; ++rt)
#pragma unroll
    for (int j = 0; j < 4; ++j) sp[rt][j] = 0.f;
#pragma unroll
  for (int c = 0; c < 4; ++c) {
    int colLocal = c * 16 + low;
    bf8 qv = *reinterpret_cast<const bf8*>(&lds[LDS_B + wave * 4096 + colLocal * 64 + qq * 16]);
#pragma unroll
    for (int rt = 0; rt < 8; ++rt) {
      float qf = bs2f((ushort)qv[rt]);
#pragma unroll
      for (int j = 0; j < 4; ++j) sp[rt][j] += accK[rt][c][j] * qf;
    }
  }
  // reduce over the 16-lane col group (xor on low 4 bits stays within quad)
#pragma unroll
  for (int mask = 1; mask <= 8; mask <<= 1)
#pragma unroll
    for (int rt = 0; rt < 8; ++rt)
#pragma unroll
      for (int j = 0; j < 4; ++j) sp[rt][j] += __shfl_xor(sp[rt][j], mask);
  // softmax over k=j (4 values, in-lane); scale 1/sqrt(64)
  float attn[8][4];
#pragma unroll
  for (int rt = 0; rt < 8; ++rt) {
    float s0 = sp[rt][0] * 0.125f, s1 = sp[rt][1] * 0.125f;
    float s2 = sp[rt][2] * 0.125f, s3 = sp[rt][3] * 0.125f;
    float m = fmaxf(fmaxf(s0, s1), fmaxf(s2, s3));
    float p0 = __expf(s0 - m), p1 = __expf(s1 - m);
    float p2 = __expf(s2 - m), p3 = __expf(s3 - m);
    float r = 1.f / (p0 + p1 + p2 + p3);
    attn[rt][0] = p0 * r; attn[rt][1] = p1 * r;
    attn[rt][2] = p2 * r; attn[rt][3] = p3 * r;
  }
  __syncthreads();   // all QH reads done; region B reusable for CTX

  // ---- Phase 3: V-proj  accV[rt][c] ----
  f32x4 accV[8][4];
#pragma unroll
  for (int rt = 0; rt < 8; ++rt)
#pragma unroll
    for (int c = 0; c < 4; ++c) accV[rt][c] = (f32x4){0.f, 0.f, 0.f, 0.f};
  {
    const ushort* wv = wf + (size_t)WSZ;
    for (int ks = 0; ks < 16; ++ks) {
      int kbyte = ks * 64 + qq * 16;
      bf8 a[8];
#pragma unroll
      for (int rt = 0; rt < 8; ++rt)
        a[rt] = *reinterpret_cast<const bf8*>(&lds[LDS_E + swz(rt * 16 + low, kbyte)]);
      bf8 bv_[4];
#pragma unroll
      for (int c = 0; c < 4; ++c) {
        size_t fo = ((size_t)((ct0 + c) * 16 + ks) * 64 + lane) * 8;
        bv_[c] = *reinterpret_cast<const bf8*>(wv + fo);
      }
#pragma unroll
      for (int c = 0; c < 4; ++c)
#pragma unroll
        for (int rt = 0; rt < 8; ++rt)
          accV[rt][c] = __builtin_amdgcn_mfma_f32_16x16x32_bf16(a[rt], bv_[c], accV[rt][c], 0, 0, 0);
    }
  }

  // ---- Phase 4: CTX in-register (attn sums to 1 -> +bv), write bf16 to region B ----
  float vb[4];
#pragma unroll
  for (int c = 0; c < 4; ++c) vb[c] = ipb[1024 + (ct0 + c) * 16 + low];
#pragma unroll
  for (int rt = 0; rt < 8; ++rt)
#pragma unroll
    for (int c = 0; c < 4; ++c) {
      float ctx = vb[c]
                + attn[rt][0] * accV[rt][c][0] + attn[rt][1] * accV[rt][c][1]
                + attn[rt][2] * accV[rt][c][2] + attn[rt][3] * accV[rt][c][3];
      int g = rt * 4 + qq;
      int col2 = ((ct0 + c) * 16 + low) * 2;
      *reinterpret_cast<ushort*>(&lds[LDS_B + g * 1024 + (col2 ^ ((g & 7) << 4))]) = f2bs(ctx);
    }
  __syncthreads();

  // ---- Phase 5: out-proj  accO[rtq][c] = CTX @ WoT + bo ----
  f32x4 accO[2][4];
#pragma unroll
  for (int rt = 0; rt < 2; ++rt)
#pragma unroll
    for (int c = 0; c < 4; ++c) accO[rt][c] = (f32x4){0.f, 0.f, 0.f, 0.f};
  {
    const ushort* wo = wf + 3 * (size_t)WSZ;
    for (int ks = 0; ks < 16; ++ks) {
      int kbyte = ks * 64 + qq * 16;
      bf8 aO[2];
#pragma unroll
      for (int rt = 0; rt < 2; ++rt)
        aO[rt] = *reinterpret_cast<const bf8*>(&lds[LDS_B + swz(rt * 16 + low, kbyte)]);
      bf8 bo_[4];
#pragma unroll
      for (int c = 0; c < 4; ++c) {
        size_t fo = ((size_t)((ct0 + c) * 16 + ks) * 64 + lane) * 8;
        bo_[c] = *reinterpret_cast<const bf8*>(wo + fo);
      }
#pragma unroll
      for (int c = 0; c < 4; ++c)
#pragma unroll
        for (int rt = 0; rt < 2; ++rt)
          accO[rt][c] = __builtin_amdgcn_mfma_f32_16x16x32_bf16(aO[rt], bo_[c], accO[rt][c], 0, 0, 0);
    }
  }
#pragma unroll
  for (int c = 0; c < 4; ++c) {
    int col = (ct0 + c) * 16 + low;
    float ob = opb[col];
#pragma unroll
    for (int rt = 0; rt < 2; ++rt)
#pragma unroll
      for (int j = 0; j < 4; ++j) {
        int g = rt * 16 + qq * 4 + j;
        out[((size_t)blk * GB + g) * DIM + col] = accO[rt][c][j] + ob;
      }
  }
}

extern "C" void kernel_launch(void* const* d_in, const int* in_sizes, int n_in,
                              void* d_out, int out_size, void* d_ws, size_t ws_size,
                              hipStream_t stream) {
  const float* x   = (const float*)d_in[0];
  const float* pos = (const float*)d_in[1];
  const float* ipw = (const float*)d_in[2];
  const float* ipb = (const float*)d_in[3];
  const float* opw = (const float*)d_in[4];
  const float* opb = (const float*)d_in[5];
  ushort* wsf = (ushort*)d_ws;  // 4 * 262144 bf16 = 2 MB

  prep_w<<<512, 256, 0, stream>>>(ipw, opw, wsf);

  hipFuncSetAttribute(reinterpret_cast<const void*>(tdsa),
                      hipFuncAttributeMaxDynamicSharedMemorySize, LDS_TOT);
  tdsa<<<512, 512, LDS_TOT, stream>>>(x, pos, ipb, opb, wsf, (float*)d_out);
}